// Round 6
// baseline (285.821 us; speedup 1.0000x reference)
//
#include <hip/hip_runtime.h>
#include <hip/hip_bf16.h>

typedef __attribute__((ext_vector_type(8))) short short8;
typedef __attribute__((ext_vector_type(4))) short bfx4;
typedef __attribute__((ext_vector_type(4))) float floatx4;
typedef __attribute__((ext_vector_type(4))) __fp16 h4_t;
typedef __attribute__((ext_vector_type(2))) __fp16 h2_t;
typedef __attribute__((ext_vector_type(8))) __fp16 h8_t;

#define BATCH 4
#define SEQ 2048
#define D_MODEL 1024
#define NH 16
#define HD 64
#define ELEMS 8388608   // B*S*D = 4*2048*1024
#define WELEMS 1048576  // 1024*1024

// fp32 -> bf16 round-to-nearest-even
__device__ __forceinline__ unsigned short f2bf(float f) {
    union { float f; unsigned u; } x; x.f = f;
    unsigned r = x.u + 0x7FFFu + ((x.u >> 16) & 1u);
    return (unsigned short)(r >> 16);
}
__device__ __forceinline__ unsigned short f2h(float f) {
    union { __fp16 h; unsigned short u; } x;
    x.h = (__fp16)f;
    return x.u;
}

#if __has_builtin(__builtin_amdgcn_exp2f)
__device__ __forceinline__ float fexp2(float x) { return __builtin_amdgcn_exp2f(x); }
#else
__device__ __forceinline__ float fexp2(float x) { return exp2f(x); }
#endif

// async global->LDS, 16B per lane; HW dest = wave-uniform base + lane*16
__device__ __forceinline__ void gll16(const void* g, const void* l) {
    __builtin_amdgcn_global_load_lds(
        (const __attribute__((address_space(1))) void*)g,
        (__attribute__((address_space(3))) void*)l,
        16, 0, 0);
}

// NOTE (session post-mortems):
//  - R1: 8-phase 256^2 counted-vmcnt GEMM port regressed. Abandoned.
//  - R2: double-buffered attn regressed: compiler drains vmcnt(0) before the
//    first ds_read of the other buffer. Do not software-pipeline
//    global_load_lds here.
//  - R3: 128^2 GEMM tiles > 128x256 at K=1024 (total 317->302).
//  - R4: attn7 (4 acc sets + 8 bq) spilled at the 128-VGPR cap: FETCH 397MB/
//    WRITE 162MB scratch signature. Register budget is the hard wall.
//  - R5: attn8 (2 acc sets, K/V-read reuse across 2 Q-frags) WORKED:
//    107us, VGPR 92, no spill, conflicts 6.55M->4.46M. Total 281.8.
//  - R6 (this round): attn8 FETCH 110MB vs ~35MB unique K/V+Q = 3x over-fetch
//    because the 16 j-blocks sharing a bh (same K/V tiles) round-robin across
//    8 XCDs -> every XCD re-fetches through its private L2; each gll16 eats
//    L3/HBM latency in the drain. T1 XCD swizzle (hw id %8 = XCD) co-locates
//    all j of one bh on one XCD (working set 2MB < 4MB L2). Same A-panel
//    chunking for both GEMMs. Pure index permutation - no schedule risk.

// ---------------------------------------------------------------------------
// cvt: x (8M), wq|wk|wv (3M, concatenated), wo (1M) fp32 -> bf16
// ---------------------------------------------------------------------------
__global__ __launch_bounds__(256)
void cvt_kernel(const float* __restrict__ x,  const float* __restrict__ wq,
                const float* __restrict__ wk, const float* __restrict__ wv,
                const float* __restrict__ wo,
                unsigned short* __restrict__ xbf,
                unsigned short* __restrict__ wqkv,
                unsigned short* __restrict__ wobf)
{
    size_t idx = ((size_t)blockIdx.x * 256 + threadIdx.x) * 8;
    const float* src; unsigned short* dst; size_t off;
    if (idx < (size_t)ELEMS)                    { src = x;  dst = xbf;             off = idx; }
    else if (idx < (size_t)ELEMS + WELEMS)      { src = wq; dst = wqkv;            off = idx - ELEMS; }
    else if (idx < (size_t)ELEMS + 2 * WELEMS)  { src = wk; dst = wqkv + WELEMS;   off = idx - ELEMS - WELEMS; }
    else if (idx < (size_t)ELEMS + 3 * WELEMS)  { src = wv; dst = wqkv + 2*WELEMS; off = idx - ELEMS - 2*WELEMS; }
    else                                        { src = wo; dst = wobf;            off = idx - ELEMS - 3*WELEMS; }
    floatx4 a = *(const floatx4*)(src + off);
    floatx4 b = *(const floatx4*)(src + off + 4);
    short8 v;
#pragma unroll
    for (int d = 0; d < 4; d++) { v[d] = (short)f2bf(a[d]); v[4+d] = (short)f2bf(b[d]); }
    *(short8*)(dst + off) = v;
}

// ---------------------------------------------------------------------------
// QKV GEMM, 128x128 tile (R3 proven): A=x_bf [8192,1024], B=wqkv_bf
// [3072,1024] (NT), staged via global_load_lds with inverse-XOR-swizzled
// source. BK=64, 32 KiB LDS. 1D grid 1536 with XCD swizzle: hw id %8 = XCD;
// chunk of 192 work ids per XCD = 8 A-panels (2MB in L2) x 24 ny.
// ---------------------------------------------------------------------------
__global__ __launch_bounds__(256, 2)
void gemm_qkv3_kernel(const unsigned short* __restrict__ A,
                      const unsigned short* __restrict__ B,
                      unsigned short* __restrict__ Qb,
                      unsigned short* __restrict__ Kb,
                      unsigned short* __restrict__ Vb)
{
    __shared__ __align__(16) unsigned short As[128 * 64];
    __shared__ __align__(16) unsigned short Bs[128 * 64];

    const int t = threadIdx.x;
    const int wave = t >> 6, lane = t & 63;
    const int lm = lane & 15, lq = lane >> 4;
    const int wrow = (wave >> 1) * 64, wcol = (wave & 1) * 64;

    // XCD swizzle: nwg=1536=8*192; wk chunk [xcd*192, +192) -> mx in [xcd*8,+8)
    const int orig = blockIdx.x;
    const int wk = (orig & 7) * 192 + (orig >> 3);
    const int mx = wk / 24, ny = wk % 24;
    const int m0 = mx * 128, n0 = ny * 128;

    const int lrow = lane >> 3, lg = lane & 7;
    const int gsw = lg ^ lrow;

    floatx4 acc[4][4] = {};

    for (int k0 = 0; k0 < 1024; k0 += 64) {
        __syncthreads();
#pragma unroll
        for (int i = 0; i < 4; i++) {
            int rows8 = wave * 32 + i * 8;
            gll16(A + (size_t)(m0 + rows8 + lrow) * 1024 + k0 + gsw * 8, As + rows8 * 64);
            gll16(B + (size_t)(n0 + rows8 + lrow) * 1024 + k0 + gsw * 8, Bs + rows8 * 64);
        }
        __syncthreads();

#pragma unroll
        for (int c = 0; c < 2; c++) {
            short8 af[4], bfr[4];
#pragma unroll
            for (int i = 0; i < 4; i++) {
                int ra = wrow + i * 16 + lm;
                int g = c * 4 + lq;
                af[i] = *(const short8*)(As + (ra * 8 + (g ^ (ra & 7))) * 8);
            }
#pragma unroll
            for (int j = 0; j < 4; j++) {
                int rb = wcol + j * 16 + lm;
                int g = c * 4 + lq;
                bfr[j] = *(const short8*)(Bs + (rb * 8 + (g ^ (rb & 7))) * 8);
            }
#pragma unroll
            for (int i = 0; i < 4; i++)
#pragma unroll
                for (int j = 0; j < 4; j++)
                    acc[i][j] = __builtin_amdgcn_mfma_f32_16x16x32_bf16(
                        af[i], bfr[j], acc[i][j], 0, 0, 0);
        }
    }

    const int z = n0 >> 10;   // 0=Q 1=K 2=V, uniform per block
#pragma unroll
    for (int i = 0; i < 4; i++)
#pragma unroll
        for (int j = 0; j < 4; j++)
#pragma unroll
            for (int r = 0; r < 4; r++) {
                int gm = m0 + wrow + i * 16 + lq * 4 + r;
                int gn = n0 + wcol + j * 16 + lm;
                int nl = gn & 1023, h = nl >> 6, d = nl & 63;
                int b = gm >> 11, s = gm & 2047;
                float v = acc[i][j][r];
                size_t bh = (size_t)(b * NH + h);
                if (z == 0)      Qb[(bh * SEQ + s) * HD + d] = f2bf(v);
                else if (z == 1) Kb[(bh * SEQ + s) * HD + d] = f2bf(v);
                else             Vb[(bh * HD + d) * SEQ + s] = f2h(v);
            }
}

// ---------------------------------------------------------------------------
// Output projection, 128x128 tile (R3 proven): A=Ob bf16 [8192,1024],
// B=wo_bf [1024,1024] -> fp32. 1D grid 512 with XCD swizzle:
// chunk of 64 work ids per XCD = 8 A-panels (2MB) x 8 ny (wo 2MB).
// ---------------------------------------------------------------------------
__global__ __launch_bounds__(256, 2)
void gemm_out3_kernel(const unsigned short* __restrict__ A,
                      const unsigned short* __restrict__ B,
                      float* __restrict__ Out)
{
    __shared__ __align__(16) unsigned short As[128 * 64];
    __shared__ __align__(16) unsigned short Bs[128 * 64];

    const int t = threadIdx.x;
    const int wave = t >> 6, lane = t & 63;
    const int lm = lane & 15, lq = lane >> 4;
    const int wrow = (wave >> 1) * 64, wcol = (wave & 1) * 64;

    // XCD swizzle: nwg=512=8*64; wk chunk [xcd*64, +64) -> mx in [xcd*8,+8)
    const int orig = blockIdx.x;
    const int wk = (orig & 7) * 64 + (orig >> 3);
    const int mx = wk >> 3, ny = wk & 7;
    const int m0 = mx * 128, n0 = ny * 128;

    const int lrow = lane >> 3, lg = lane & 7;
    const int gsw = lg ^ lrow;

    floatx4 acc[4][4] = {};

    for (int k0 = 0; k0 < 1024; k0 += 64) {
        __syncthreads();
#pragma unroll
        for (int i = 0; i < 4; i++) {
            int rows8 = wave * 32 + i * 8;
            gll16(A + (size_t)(m0 + rows8 + lrow) * 1024 + k0 + gsw * 8, As + rows8 * 64);
            gll16(B + (size_t)(n0 + rows8 + lrow) * 1024 + k0 + gsw * 8, Bs + rows8 * 64);
        }
        __syncthreads();

#pragma unroll
        for (int c = 0; c < 2; c++) {
            short8 af[4], bfr[4];
#pragma unroll
            for (int i = 0; i < 4; i++) {
                int ra = wrow + i * 16 + lm;
                int g = c * 4 + lq;
                af[i] = *(const short8*)(As + (ra * 8 + (g ^ (ra & 7))) * 8);
            }
#pragma unroll
            for (int j = 0; j < 4; j++) {
                int rb = wcol + j * 16 + lm;
                int g = c * 4 + lq;
                bfr[j] = *(const short8*)(Bs + (rb * 8 + (g ^ (rb & 7))) * 8);
            }
#pragma unroll
            for (int i = 0; i < 4; i++)
#pragma unroll
                for (int j = 0; j < 4; j++)
                    acc[i][j] = __builtin_amdgcn_mfma_f32_16x16x32_bf16(
                        af[i], bfr[j], acc[i][j], 0, 0, 0);
        }
    }

#pragma unroll
    for (int i = 0; i < 4; i++)
#pragma unroll
        for (int j = 0; j < 4; j++)
#pragma unroll
            for (int r = 0; r < 4; r++) {
                int gm = m0 + wrow + i * 16 + lq * 4 + r;
                int gn = n0 + wcol + j * 16 + lm;
                Out[(size_t)gm * D_MODEL + gn] = acc[i][j][r];
            }
}

// ---------------------------------------------------------------------------
// Flash attention v8 + XCD swizzle (R5 proven mechanism, R6 locality):
// ONE 128-row supertile per block, 2 Q-frags per wave (rows +0,+64); every
// K/V LDS fragment read feeds 2 MFMAs at attn5's register footprint.
// 1D grid 1024 = 8 XCD chunks x 128; chunk = 8 bh x 16 j -> all 16 j-blocks
// of one bh (same K/V tiles, 512KB) co-resident on one XCD's L2.
// Within chunk j ascends -> heavy (j=0) blocks first.
// Q,K bf16 [b,h,s,d]; V f16 [b,h,d,s]; O bf16 [b,s,1024].
// Row 2047 (l=0 -> NaN) overwritten by row2047_kernel afterwards.
// ---------------------------------------------------------------------------
#define PROCESS_Q2(QI0, QI1, BQ0, BQ1, ACC0, ACC1, L0, L1, DOMASK, KT)         \
    do {                                                                       \
        _Pragma("unroll")                                                      \
        for (int jt = 0; jt < 8; jt++) {                                       \
            floatx4 sc0 = {}, sc1 = {};                                        \
            _Pragma("unroll")                                                  \
            for (int c = 0; c < 2; c++) {                                      \
                int row_ = jt * 16 + lm;                                       \
                int g_ = c * 4 + lq;                                           \
                short8 kf = *(const short8*)(Ks + (row_ * 8 + (g_ ^ (row_ & 7))) * 8); \
                sc0 = __builtin_amdgcn_mfma_f32_16x16x32_bf16(kf, BQ0[c], sc0, 0, 0, 0); \
                sc1 = __builtin_amdgcn_mfma_f32_16x16x32_bf16(kf, BQ1[c], sc1, 0, 0, 0); \
            }                                                                  \
            if (DOMASK) {                                                      \
                _Pragma("unroll")                                              \
                for (int r = 0; r < 4; r++) {                                  \
                    int kj = (KT) * 128 + jt * 16 + lq * 4 + r;                \
                    if (!(kj > (QI0))) sc0[r] = -3.2e10f;                      \
                    if (!(kj > (QI1))) sc1[r] = -3.2e10f;                      \
                }                                                              \
            }                                                                  \
            float p00 = fexp2(sc0[0] * kA), p01 = fexp2(sc0[1] * kA);          \
            float p02 = fexp2(sc0[2] * kA), p03 = fexp2(sc0[3] * kA);          \
            float p10 = fexp2(sc1[0] * kA), p11 = fexp2(sc1[1] * kA);          \
            float p12 = fexp2(sc1[2] * kA), p13 = fexp2(sc1[3] * kA);          \
            L0 += (p00 + p01) + (p02 + p03);                                   \
            L1 += (p10 + p11) + (p12 + p13);                                   \
            h2_t a0_ = __builtin_amdgcn_cvt_pkrtz(p00, p01);                   \
            h2_t b0_ = __builtin_amdgcn_cvt_pkrtz(p02, p03);                   \
            h2_t a1_ = __builtin_amdgcn_cvt_pkrtz(p10, p11);                   \
            h2_t b1_ = __builtin_amdgcn_cvt_pkrtz(p12, p13);                   \
            h4_t pf0, pf1;                                                     \
            pf0[0] = a0_[0]; pf0[1] = a0_[1]; pf0[2] = b0_[0]; pf0[3] = b0_[1];\
            pf1[0] = a1_[0]; pf1[1] = a1_[1]; pf1[2] = b1_[0]; pf1[3] = b1_[1];\
            _Pragma("unroll")                                                  \
            for (int jd = 0; jd < 4; jd++) {                                   \
                int rowv_ = jd * 16 + lm;                                      \
                int g16_ = jt * 2 + (lq >> 1);                                 \
                int slot_ = rowv_ * 16 + (g16_ ^ lm);                          \
                h4_t vf = *(const h4_t*)((const __fp16*)Vs + slot_ * 8 + (lq & 1) * 4); \
                ACC0[jd] = __builtin_amdgcn_mfma_f32_16x16x16f16(vf, pf0, ACC0[jd], 0, 0, 0); \
                ACC1[jd] = __builtin_amdgcn_mfma_f32_16x16x16f16(vf, pf1, ACC1[jd], 0, 0, 0); \
            }                                                                  \
        }                                                                      \
    } while (0)

#define WRITE_O(QROW, ACC, LV)                                                 \
    do {                                                                       \
        float l_ = LV;                                                         \
        l_ += __shfl_xor(l_, 16); l_ += __shfl_xor(l_, 32);                    \
        float inv_ = 1.0f / l_;                                                \
        _Pragma("unroll")                                                      \
        for (int jd = 0; jd < 4; jd++) {                                       \
            bfx4 o_;                                                           \
            _Pragma("unroll")                                                  \
            for (int r = 0; r < 4; r++) o_[r] = (short)f2bf(ACC[jd][r] * inv_);\
            *(bfx4*)(O + (size_t)(b * SEQ + (QROW)) * D_MODEL + h * HD + jd * 16 + lq * 4) = o_; \
        }                                                                      \
    } while (0)

__global__ __launch_bounds__(256, 2)
void attn8_kernel(const unsigned short* __restrict__ Q,
                  const unsigned short* __restrict__ K,
                  const unsigned short* __restrict__ V,
                  unsigned short* __restrict__ O)
{
    __shared__ __align__(16) unsigned short Ks[128 * 64];  // [key][d] swizzled bf16
    __shared__ __align__(16) unsigned short Vs[64 * 128];  // [d][key] swizzled f16

    const int t = threadIdx.x;
    const int wave = t >> 6, lane = t & 63;
    const int lm = lane & 15, lq = lane >> 4;

    // XCD swizzle: nwg=1024=8*128; chunk = 8 bh x 16 j per XCD
    const int orig = blockIdx.x;
    const int wkid = (orig & 7) * 128 + (orig >> 3);
    const int bh = wkid >> 4;          // 0..63
    const int j  = wkid & 15;          // supertile 0..15 (128 q rows each)

    const int q0 = j * 128 + wave * 16 + lm;
    const int q1 = q0 + 64;

    const unsigned short* Qh = Q + (size_t)bh * SEQ * HD;
    const unsigned short* Kh = K + (size_t)bh * SEQ * HD;
    const unsigned short* Vh = V + (size_t)bh * HD * SEQ;  // [d][s]

    short8 bq0[2], bq1[2];
#pragma unroll
    for (int c = 0; c < 2; c++) {
        bq0[c] = *(const short8*)(Qh + (size_t)q0 * HD + c * 32 + lq * 8);
        bq1[c] = *(const short8*)(Qh + (size_t)q1 * HD + c * 32 + lq * 8);
    }

    floatx4 acc0[4] = {}, acc1[4] = {};
    float l0 = 0.f, l1 = 0.f;
    const float kA = 0.04508422002778011f;  // log2(e)/32

    const int lrow = lane >> 3, lg = lane & 7;

    for (int kt = 15; kt >= j; kt--) {
        __syncthreads();
        // K tile: 128 keys x 64 d
#pragma unroll
        for (int i = 0; i < 4; i++) {
            int rows8 = wave * 32 + i * 8;
            gll16(Kh + (size_t)(kt * 128 + rows8 + lrow) * HD + (lg ^ lrow) * 8,
                  Ks + rows8 * 64);
        }
        // V^T tile: 64 d x 128 keys
#pragma unroll
        for (int i = 0; i < 4; i++) {
            int rows4 = wave * 16 + i * 4;
            int row = rows4 + (lane >> 4);
            int g = (lane & 15) ^ (row & 15);
            gll16(Vh + (size_t)row * SEQ + kt * 128 + g * 8, Vs + rows4 * 128);
        }
        __syncthreads();

        PROCESS_Q2(q0, q1, bq0, bq1, acc0, acc1, l0, l1, (kt == j), kt);
    }

    const int b = bh >> 4, h = bh & 15;
    WRITE_O(q0, acc0, l0);
    WRITE_O(q1, acc1, l1);
}

// ---------------------------------------------------------------------------
// Row 2047 is fully masked -> uniform softmax over ALL keys -> mean of V.
// ---------------------------------------------------------------------------
__global__ __launch_bounds__(256, 2)
void row2047_kernel(const unsigned short* __restrict__ V,
                    unsigned short* __restrict__ O)
{
    __shared__ float red[256];
    const int bh = blockIdx.x;
    const int b = bh >> 4, h = bh & 15;
    const int t = threadIdx.x;
    const int d = t & 63, seg = t >> 6;
    const __fp16* Vh = (const __fp16*)V + (size_t)bh * HD * SEQ + (size_t)d * SEQ + seg * 512;
    float s = 0.f;
    for (int i = 0; i < 512; i += 8) {
        h8_t v = *(const h8_t*)(Vh + i);
#pragma unroll
        for (int j = 0; j < 8; j++) s += (float)v[j];
    }
    red[t] = s;
    __syncthreads();
    if (seg == 0) {
        float tot = red[d] + red[64 + d] + red[128 + d] + red[192 + d];
        O[(size_t)(b * SEQ + 2047) * D_MODEL + h * HD + d] = f2bf(tot * (1.f / 2048.f));
    }
}

// ======================= fallback (ws < 72 MiB) kernels =====================
__global__ __launch_bounds__(256, 2)
void gemm_qkv_kernel(const float* __restrict__ A,
                     const float* __restrict__ W0,
                     const float* __restrict__ W1,
                     const float* __restrict__ W2,
                     unsigned short* __restrict__ O0,
                     unsigned short* __restrict__ O1,
                     unsigned short* __restrict__ O2)
{
    const int K = 1024;
    const float* W;
    unsigned short* Out;
    if (blockIdx.z == 0)      { W = W0; Out = O0; }
    else if (blockIdx.z == 1) { W = W1; Out = O1; }
    else                      { W = W2; Out = O2; }

    __shared__ __align__(16) unsigned short As[128 * 64];
    __shared__ __align__(16) unsigned short Bs[128 * 64];

    const int t = threadIdx.x;
    const int wave = t >> 6, lane = t & 63;
    const int lm = lane & 15, lq = lane >> 4;
    const int wrow = (wave >> 1) * 64, wcol = (wave & 1) * 64;
    const int m0 = blockIdx.x * 128, n0 = blockIdx.y * 128;

    floatx4 acc[4][4] = {};

    for (int k0 = 0; k0 < K; k0 += 64) {
        __syncthreads();
#pragma unroll
        for (int rr = 0; rr < 4; rr++) {
            int p = rr * 256 + t;
            int row = p >> 3, g = p & 7;
            const float* pa = A + (size_t)(m0 + row) * K + k0 + g * 8;
            const float* pw = W + (size_t)(n0 + row) * K + k0 + g * 8;
            floatx4 a0 = *(const floatx4*)pa, a1 = *(const floatx4*)(pa + 4);
            floatx4 w0 = *(const floatx4*)pw, w1 = *(const floatx4*)(pw + 4);
            short8 va, vb;
#pragma unroll
            for (int d = 0; d < 4; d++) {
                va[d]     = (short)f2bf(a0[d]);
                va[4 + d] = (short)f2bf(a1[d]);
                vb[d]     = (short)f2bf(w0[d]);
                vb[4 + d] = (short)f2bf(w1[d]);
            }
            int dst = row * 8 + (g ^ (row & 7));
            *(short8*)(As + dst * 8) = va;
            *(short8*)(Bs + dst * 8) = vb;
        }
        __syncthreads();

        short8 af[4][2], bf[4][2];
#pragma unroll
        for (int i = 0; i < 4; i++)
#pragma unroll
            for (int c = 0; c < 2; c++) {
                int ra = wrow + i * 16 + lm;
                int rb = wcol + i * 16 + lm;
                int g = c * 4 + lq;
                af[i][c] = *(const short8*)(As + (ra * 8 + (g ^ (ra & 7))) * 8);
                bf[i][c] = *(const short8*)(Bs + (rb * 8 + (g ^ (rb & 7))) * 8);
            }
#pragma unroll
        for (int i = 0; i < 4; i++)
#pragma unroll
            for (int j = 0; j < 4; j++)
#pragma unroll
                for (int c = 0; c < 2; c++)
                    acc[i][j] = __builtin_amdgcn_mfma_f32_16x16x32_bf16(
                        af[i][c], bf[j][c], acc[i][j], 0, 0, 0);
    }

    const int zi = blockIdx.z;
#pragma unroll
    for (int i = 0; i < 4; i++)
#pragma unroll
        for (int j = 0; j < 4; j++)
#pragma unroll
            for (int r = 0; r < 4; r++) {
                int gm = m0 + wrow + i * 16 + lq * 4 + r;
                int gn = n0 + wcol + j * 16 + lm;
                int b = gm >> 11, s = gm & 2047;
                int h = gn >> 6, d = gn & 63;
                if (zi == 2) {
                    Out[((size_t)(b * NH + h) * HD + d) * SEQ + s] = f2h(acc[i][j][r]);
                } else {
                    Out[((size_t)(b * NH + h) * SEQ + s) * HD + d] = f2bf(acc[i][j][r]);
                }
            }
}

__global__ __launch_bounds__(256, 2)
void gemm_out_kernel(const unsigned short* __restrict__ Abf,
                     const float* __restrict__ W,
                     float* __restrict__ Out)
{
    const int K = 1024;
    __shared__ __align__(16) unsigned short As[128 * 64];
    __shared__ __align__(16) unsigned short Bs[128 * 64];

    const int t = threadIdx.x;
    const int wave = t >> 6, lane = t & 63;
    const int lm = lane & 15, lq = lane >> 4;
    const int wrow = (wave >> 1) * 64, wcol = (wave & 1) * 64;
    const int m0 = blockIdx.x * 128, n0 = blockIdx.y * 128;

    floatx4 acc[4][4] = {};

    for (int k0 = 0; k0 < K; k0 += 64) {
        __syncthreads();
#pragma unroll
        for (int rr = 0; rr < 4; rr++) {
            int p = rr * 256 + t;
            int row = p >> 3, g = p & 7;
            short8 va = *(const short8*)(Abf + (size_t)(m0 + row) * K + k0 + g * 8);
            const float* pw = W + (size_t)(n0 + row) * K + k0 + g * 8;
            floatx4 w0 = *(const floatx4*)pw, w1 = *(const floatx4*)(pw + 4);
            short8 vb;
#pragma unroll
            for (int d = 0; d < 4; d++) {
                vb[d]     = (short)f2bf(w0[d]);
                vb[4 + d] = (short)f2bf(w1[d]);
            }
            int dst = row * 8 + (g ^ (row & 7));
            *(short8*)(As + dst * 8) = va;
            *(short8*)(Bs + dst * 8) = vb;
        }
        __syncthreads();

        short8 af[4][2], bf[4][2];
#pragma unroll
        for (int i = 0; i < 4; i++)
#pragma unroll
            for (int c = 0; c < 2; c++) {
                int ra = wrow + i * 16 + lm;
                int rb = wcol + i * 16 + lm;
                int g = c * 4 + lq;
                af[i][c] = *(const short8*)(As + (ra * 8 + (g ^ (ra & 7))) * 8);
                bf[i][c] = *(const short8*)(Bs + (rb * 8 + (g ^ (rb & 7))) * 8);
            }
#pragma unroll
        for (int i = 0; i < 4; i++)
#pragma unroll
            for (int j = 0; j < 4; j++)
#pragma unroll
                for (int c = 0; c < 2; c++)
                    acc[i][j] = __builtin_amdgcn_mfma_f32_16x16x32_bf16(
                        af[i][c], bf[j][c], acc[i][j], 0, 0, 0);
    }

#pragma unroll
    for (int i = 0; i < 4; i++)
#pragma unroll
        for (int j = 0; j < 4; j++)
#pragma unroll
            for (int r = 0; r < 4; r++) {
                int gm = m0 + wrow + i * 16 + lq * 4 + r;
                int gn = n0 + wcol + j * 16 + lm;
                Out[(size_t)gm * D_MODEL + gn] = acc[i][j][r];
            }
}

extern "C" void kernel_launch(void* const* d_in, const int* in_sizes, int n_in,
                              void* d_out, int out_size, void* d_ws, size_t ws_size,
                              hipStream_t stream) {
    const float* x  = (const float*)d_in[0];
    const float* wq = (const float*)d_in[1];
    const float* wk = (const float*)d_in[2];
    const float* wv = (const float*)d_in[3];
    const float* wo = (const float*)d_in[4];

    unsigned short* ws = (unsigned short*)d_ws;
    const bool fast = ws_size >= (size_t)36 * 1024 * 1024 * 2;  // 72 MiB

    if (fast) {
        unsigned short* xbf  = ws;                     // 8M elems; reused as Ob
        unsigned short* wqkv = ws + (size_t)ELEMS;     // 3M
        unsigned short* wobf = ws + (size_t)ELEMS + 3 * WELEMS;  // 1M
        unsigned short* Qb   = ws + (size_t)ELEMS + 4 * WELEMS;  // 8M
        unsigned short* Kb   = Qb + ELEMS;
        unsigned short* Vb   = Kb + ELEMS;
        unsigned short* Ob   = xbf;                    // x_bf dead after QKV GEMM

        cvt_kernel<<<6144, 256, 0, stream>>>(x, wq, wk, wv, wo, xbf, wqkv, wobf);
        gemm_qkv3_kernel<<<1536, 256, 0, stream>>>(xbf, wqkv, Qb, Kb, Vb);
        attn8_kernel<<<1024, 256, 0, stream>>>(Qb, Kb, Vb, Ob);
        row2047_kernel<<<BATCH * NH, 256, 0, stream>>>(Vb, Ob);
        gemm_out3_kernel<<<512, 256, 0, stream>>>(Ob, wobf, (float*)d_out);
    } else {
        unsigned short* Qb = ws;
        unsigned short* Kb = Qb + ELEMS;
        unsigned short* Vb = Kb + ELEMS;
        unsigned short* Ob = Vb + ELEMS;

        gemm_qkv_kernel<<<dim3(64, 8, 3), 256, 0, stream>>>(x, wq, wk, wv, Qb, Kb, Vb);
        attn8_kernel<<<1024, 256, 0, stream>>>(Qb, Kb, Vb, Ob);
        row2047_kernel<<<BATCH * NH, 256, 0, stream>>>(Vb, Ob);
        gemm_out_kernel<<<dim3(64, 8), 256, 0, stream>>>(Ob, wo, (float*)d_out);
    }
}

// Round 7
// 268.527 us; speedup vs baseline: 1.0644x; 1.0644x over previous
//
#include <hip/hip_runtime.h>
#include <hip/hip_bf16.h>

typedef __attribute__((ext_vector_type(8))) short short8;
typedef __attribute__((ext_vector_type(4))) short bfx4;
typedef __attribute__((ext_vector_type(4))) float floatx4;
typedef __attribute__((ext_vector_type(4))) __fp16 h4_t;
typedef __attribute__((ext_vector_type(2))) __fp16 h2_t;
typedef __attribute__((ext_vector_type(8))) __fp16 h8_t;

#define BATCH 4
#define SEQ 2048
#define D_MODEL 1024
#define NH 16
#define HD 64
#define ELEMS 8388608   // B*S*D = 4*2048*1024
#define WELEMS 1048576  // 1024*1024

// fp32 -> bf16 round-to-nearest-even
__device__ __forceinline__ unsigned short f2bf(float f) {
    union { float f; unsigned u; } x; x.f = f;
    unsigned r = x.u + 0x7FFFu + ((x.u >> 16) & 1u);
    return (unsigned short)(r >> 16);
}
__device__ __forceinline__ unsigned short f2h(float f) {
    union { __fp16 h; unsigned short u; } x;
    x.h = (__fp16)f;
    return x.u;
}

#if __has_builtin(__builtin_amdgcn_exp2f)
__device__ __forceinline__ float fexp2(float x) { return __builtin_amdgcn_exp2f(x); }
#else
__device__ __forceinline__ float fexp2(float x) { return exp2f(x); }
#endif

// async global->LDS, 16B per lane; HW dest = wave-uniform base + lane*16
__device__ __forceinline__ void gll16(const void* g, const void* l) {
    __builtin_amdgcn_global_load_lds(
        (const __attribute__((address_space(1))) void*)g,
        (__attribute__((address_space(3))) void*)l,
        16, 0, 0);
}

// NOTE (session post-mortems):
//  - R1: 8-phase 256^2 counted-vmcnt GEMM port regressed. Abandoned.
//  - R2: double-buffered attn regressed: compiler drains vmcnt(0) before the
//    first ds_read of the other buffer. Do not software-pipeline
//    global_load_lds here.
//  - R3: 128^2 GEMM tiles > 128x256 at K=1024 (total 317->302).
//  - R4: attn7 (4 acc sets + 8 bq) spilled at the 128-VGPR cap. Register
//    budget is the hard wall; FETCH/WRITE blowup is the spill signature.
//  - R5: attn8 (2 acc sets, K/V-read reuse across 2 Q-frags): 107us, no
//    spill. Total 281.8.
//  - R6: attn XCD swizzle WIN (107->86.5us, FETCH 110->24.6MB). GEMM XCD
//    swizzle REGRESSED ~24us: my chunk iterated ny fastest -> resident set
//    per XCD = all 24 B panels (6.75MB > 4MB L2), B shared only 2.7-way.
//    The DEFAULT x-fastest 2D dispatch already gives 8mx x 8ny = 4MB with
//    8-way B sharing. Lesson: compute the per-XCD concurrent working set
//    BEFORE swizzling; default round-robin can already be optimal.
//  - R7 (this round): recombine proven states: GEMMs from R5 (plain 2D
//    grid), attn from R6 (swizzled).

// ---------------------------------------------------------------------------
// cvt: x (8M), wq|wk|wv (3M, concatenated), wo (1M) fp32 -> bf16
// ---------------------------------------------------------------------------
__global__ __launch_bounds__(256)
void cvt_kernel(const float* __restrict__ x,  const float* __restrict__ wq,
                const float* __restrict__ wk, const float* __restrict__ wv,
                const float* __restrict__ wo,
                unsigned short* __restrict__ xbf,
                unsigned short* __restrict__ wqkv,
                unsigned short* __restrict__ wobf)
{
    size_t idx = ((size_t)blockIdx.x * 256 + threadIdx.x) * 8;
    const float* src; unsigned short* dst; size_t off;
    if (idx < (size_t)ELEMS)                    { src = x;  dst = xbf;             off = idx; }
    else if (idx < (size_t)ELEMS + WELEMS)      { src = wq; dst = wqkv;            off = idx - ELEMS; }
    else if (idx < (size_t)ELEMS + 2 * WELEMS)  { src = wk; dst = wqkv + WELEMS;   off = idx - ELEMS - WELEMS; }
    else if (idx < (size_t)ELEMS + 3 * WELEMS)  { src = wv; dst = wqkv + 2*WELEMS; off = idx - ELEMS - 2*WELEMS; }
    else                                        { src = wo; dst = wobf;            off = idx - ELEMS - 3*WELEMS; }
    floatx4 a = *(const floatx4*)(src + off);
    floatx4 b = *(const floatx4*)(src + off + 4);
    short8 v;
#pragma unroll
    for (int d = 0; d < 4; d++) { v[d] = (short)f2bf(a[d]); v[4+d] = (short)f2bf(b[d]); }
    *(short8*)(dst + off) = v;
}

// ---------------------------------------------------------------------------
// QKV GEMM, 128x128 tile (R3/R5 proven, default 2D dispatch): A=x_bf
// [8192,1024], B=wqkv_bf [3072,1024] (NT), staged via global_load_lds with
// inverse-XOR-swizzled source. BK=64, 32 KiB LDS. Grid (64,24).
// Default x-fastest dispatch gives per-XCD resident set 8mx x 8ny = 4MB
// with 8-way B sharing (R6 lesson: don't swizzle this).
// ---------------------------------------------------------------------------
__global__ __launch_bounds__(256, 2)
void gemm_qkv3_kernel(const unsigned short* __restrict__ A,
                      const unsigned short* __restrict__ B,
                      unsigned short* __restrict__ Qb,
                      unsigned short* __restrict__ Kb,
                      unsigned short* __restrict__ Vb)
{
    __shared__ __align__(16) unsigned short As[128 * 64];
    __shared__ __align__(16) unsigned short Bs[128 * 64];

    const int t = threadIdx.x;
    const int wave = t >> 6, lane = t & 63;
    const int lm = lane & 15, lq = lane >> 4;
    const int wrow = (wave >> 1) * 64, wcol = (wave & 1) * 64;
    const int m0 = blockIdx.x * 128, n0 = blockIdx.y * 128;
    const int lrow = lane >> 3, lg = lane & 7;
    const int gsw = lg ^ lrow;

    floatx4 acc[4][4] = {};

    for (int k0 = 0; k0 < 1024; k0 += 64) {
        __syncthreads();
#pragma unroll
        for (int i = 0; i < 4; i++) {
            int rows8 = wave * 32 + i * 8;
            gll16(A + (size_t)(m0 + rows8 + lrow) * 1024 + k0 + gsw * 8, As + rows8 * 64);
            gll16(B + (size_t)(n0 + rows8 + lrow) * 1024 + k0 + gsw * 8, Bs + rows8 * 64);
        }
        __syncthreads();

#pragma unroll
        for (int c = 0; c < 2; c++) {
            short8 af[4], bfr[4];
#pragma unroll
            for (int i = 0; i < 4; i++) {
                int ra = wrow + i * 16 + lm;
                int g = c * 4 + lq;
                af[i] = *(const short8*)(As + (ra * 8 + (g ^ (ra & 7))) * 8);
            }
#pragma unroll
            for (int j = 0; j < 4; j++) {
                int rb = wcol + j * 16 + lm;
                int g = c * 4 + lq;
                bfr[j] = *(const short8*)(Bs + (rb * 8 + (g ^ (rb & 7))) * 8);
            }
#pragma unroll
            for (int i = 0; i < 4; i++)
#pragma unroll
                for (int j = 0; j < 4; j++)
                    acc[i][j] = __builtin_amdgcn_mfma_f32_16x16x32_bf16(
                        af[i], bfr[j], acc[i][j], 0, 0, 0);
        }
    }

    const int z = n0 >> 10;   // 0=Q 1=K 2=V, uniform per block
#pragma unroll
    for (int i = 0; i < 4; i++)
#pragma unroll
        for (int j = 0; j < 4; j++)
#pragma unroll
            for (int r = 0; r < 4; r++) {
                int gm = m0 + wrow + i * 16 + lq * 4 + r;
                int gn = n0 + wcol + j * 16 + lm;
                int nl = gn & 1023, h = nl >> 6, d = nl & 63;
                int b = gm >> 11, s = gm & 2047;
                float v = acc[i][j][r];
                size_t bh = (size_t)(b * NH + h);
                if (z == 0)      Qb[(bh * SEQ + s) * HD + d] = f2bf(v);
                else if (z == 1) Kb[(bh * SEQ + s) * HD + d] = f2bf(v);
                else             Vb[(bh * HD + d) * SEQ + s] = f2h(v);
            }
}

// ---------------------------------------------------------------------------
// Output projection, 128x128 tile (R3/R5 proven, default 2D dispatch):
// A=Ob bf16 [8192,1024], B=wo_bf [1024,1024] -> fp32. Grid (64,8).
// ---------------------------------------------------------------------------
__global__ __launch_bounds__(256, 2)
void gemm_out3_kernel(const unsigned short* __restrict__ A,
                      const unsigned short* __restrict__ B,
                      float* __restrict__ Out)
{
    __shared__ __align__(16) unsigned short As[128 * 64];
    __shared__ __align__(16) unsigned short Bs[128 * 64];

    const int t = threadIdx.x;
    const int wave = t >> 6, lane = t & 63;
    const int lm = lane & 15, lq = lane >> 4;
    const int wrow = (wave >> 1) * 64, wcol = (wave & 1) * 64;
    const int m0 = blockIdx.x * 128, n0 = blockIdx.y * 128;
    const int lrow = lane >> 3, lg = lane & 7;
    const int gsw = lg ^ lrow;

    floatx4 acc[4][4] = {};

    for (int k0 = 0; k0 < 1024; k0 += 64) {
        __syncthreads();
#pragma unroll
        for (int i = 0; i < 4; i++) {
            int rows8 = wave * 32 + i * 8;
            gll16(A + (size_t)(m0 + rows8 + lrow) * 1024 + k0 + gsw * 8, As + rows8 * 64);
            gll16(B + (size_t)(n0 + rows8 + lrow) * 1024 + k0 + gsw * 8, Bs + rows8 * 64);
        }
        __syncthreads();

#pragma unroll
        for (int c = 0; c < 2; c++) {
            short8 af[4], bfr[4];
#pragma unroll
            for (int i = 0; i < 4; i++) {
                int ra = wrow + i * 16 + lm;
                int g = c * 4 + lq;
                af[i] = *(const short8*)(As + (ra * 8 + (g ^ (ra & 7))) * 8);
            }
#pragma unroll
            for (int j = 0; j < 4; j++) {
                int rb = wcol + j * 16 + lm;
                int g = c * 4 + lq;
                bfr[j] = *(const short8*)(Bs + (rb * 8 + (g ^ (rb & 7))) * 8);
            }
#pragma unroll
            for (int i = 0; i < 4; i++)
#pragma unroll
                for (int j = 0; j < 4; j++)
                    acc[i][j] = __builtin_amdgcn_mfma_f32_16x16x32_bf16(
                        af[i], bfr[j], acc[i][j], 0, 0, 0);
        }
    }

#pragma unroll
    for (int i = 0; i < 4; i++)
#pragma unroll
        for (int j = 0; j < 4; j++)
#pragma unroll
            for (int r = 0; r < 4; r++) {
                int gm = m0 + wrow + i * 16 + lq * 4 + r;
                int gn = n0 + wcol + j * 16 + lm;
                Out[(size_t)gm * D_MODEL + gn] = acc[i][j][r];
            }
}

// ---------------------------------------------------------------------------
// Flash attention v8 + XCD swizzle (R5 mechanism + R6 locality, both proven):
// ONE 128-row supertile per block, 2 Q-frags per wave (rows +0,+64); every
// K/V LDS fragment read feeds 2 MFMAs at attn5's register footprint.
// 1D grid 1024 = 8 XCD chunks x 128; chunk = 8 bh x 16 j -> all 16 j-blocks
// of one bh (same K/V tiles, 512KB) co-resident on one XCD's L2
// (R6 measured: FETCH 110->24.6MB, dur 107->86.5us).
// Q,K bf16 [b,h,s,d]; V f16 [b,h,d,s]; O bf16 [b,s,1024].
// Row 2047 (l=0 -> NaN) overwritten by row2047_kernel afterwards.
// ---------------------------------------------------------------------------
#define PROCESS_Q2(QI0, QI1, BQ0, BQ1, ACC0, ACC1, L0, L1, DOMASK, KT)         \
    do {                                                                       \
        _Pragma("unroll")                                                      \
        for (int jt = 0; jt < 8; jt++) {                                       \
            floatx4 sc0 = {}, sc1 = {};                                        \
            _Pragma("unroll")                                                  \
            for (int c = 0; c < 2; c++) {                                      \
                int row_ = jt * 16 + lm;                                       \
                int g_ = c * 4 + lq;                                           \
                short8 kf = *(const short8*)(Ks + (row_ * 8 + (g_ ^ (row_ & 7))) * 8); \
                sc0 = __builtin_amdgcn_mfma_f32_16x16x32_bf16(kf, BQ0[c], sc0, 0, 0, 0); \
                sc1 = __builtin_amdgcn_mfma_f32_16x16x32_bf16(kf, BQ1[c], sc1, 0, 0, 0); \
            }                                                                  \
            if (DOMASK) {                                                      \
                _Pragma("unroll")                                              \
                for (int r = 0; r < 4; r++) {                                  \
                    int kj = (KT) * 128 + jt * 16 + lq * 4 + r;                \
                    if (!(kj > (QI0))) sc0[r] = -3.2e10f;                      \
                    if (!(kj > (QI1))) sc1[r] = -3.2e10f;                      \
                }                                                              \
            }                                                                  \
            float p00 = fexp2(sc0[0] * kA), p01 = fexp2(sc0[1] * kA);          \
            float p02 = fexp2(sc0[2] * kA), p03 = fexp2(sc0[3] * kA);          \
            float p10 = fexp2(sc1[0] * kA), p11 = fexp2(sc1[1] * kA);          \
            float p12 = fexp2(sc1[2] * kA), p13 = fexp2(sc1[3] * kA);          \
            L0 += (p00 + p01) + (p02 + p03);                                   \
            L1 += (p10 + p11) + (p12 + p13);                                   \
            h2_t a0_ = __builtin_amdgcn_cvt_pkrtz(p00, p01);                   \
            h2_t b0_ = __builtin_amdgcn_cvt_pkrtz(p02, p03);                   \
            h2_t a1_ = __builtin_amdgcn_cvt_pkrtz(p10, p11);                   \
            h2_t b1_ = __builtin_amdgcn_cvt_pkrtz(p12, p13);                   \
            h4_t pf0, pf1;                                                     \
            pf0[0] = a0_[0]; pf0[1] = a0_[1]; pf0[2] = b0_[0]; pf0[3] = b0_[1];\
            pf1[0] = a1_[0]; pf1[1] = a1_[1]; pf1[2] = b1_[0]; pf1[3] = b1_[1];\
            _Pragma("unroll")                                                  \
            for (int jd = 0; jd < 4; jd++) {                                   \
                int rowv_ = jd * 16 + lm;                                      \
                int g16_ = jt * 2 + (lq >> 1);                                 \
                int slot_ = rowv_ * 16 + (g16_ ^ lm);                          \
                h4_t vf = *(const h4_t*)((const __fp16*)Vs + slot_ * 8 + (lq & 1) * 4); \
                ACC0[jd] = __builtin_amdgcn_mfma_f32_16x16x16f16(vf, pf0, ACC0[jd], 0, 0, 0); \
                ACC1[jd] = __builtin_amdgcn_mfma_f32_16x16x16f16(vf, pf1, ACC1[jd], 0, 0, 0); \
            }                                                                  \
        }                                                                      \
    } while (0)

#define WRITE_O(QROW, ACC, LV)                                                 \
    do {                                                                       \
        float l_ = LV;                                                         \
        l_ += __shfl_xor(l_, 16); l_ += __shfl_xor(l_, 32);                    \
        float inv_ = 1.0f / l_;                                                \
        _Pragma("unroll")                                                      \
        for (int jd = 0; jd < 4; jd++) {                                       \
            bfx4 o_;                                                           \
            _Pragma("unroll")                                                  \
            for (int r = 0; r < 4; r++) o_[r] = (short)f2bf(ACC[jd][r] * inv_);\
            *(bfx4*)(O + (size_t)(b * SEQ + (QROW)) * D_MODEL + h * HD + jd * 16 + lq * 4) = o_; \
        }                                                                      \
    } while (0)

__global__ __launch_bounds__(256, 2)
void attn8_kernel(const unsigned short* __restrict__ Q,
                  const unsigned short* __restrict__ K,
                  const unsigned short* __restrict__ V,
                  unsigned short* __restrict__ O)
{
    __shared__ __align__(16) unsigned short Ks[128 * 64];  // [key][d] swizzled bf16
    __shared__ __align__(16) unsigned short Vs[64 * 128];  // [d][key] swizzled f16

    const int t = threadIdx.x;
    const int wave = t >> 6, lane = t & 63;
    const int lm = lane & 15, lq = lane >> 4;

    // XCD swizzle: nwg=1024=8*128; chunk = 8 bh x 16 j per XCD
    const int orig = blockIdx.x;
    const int wkid = (orig & 7) * 128 + (orig >> 3);
    const int bh = wkid >> 4;          // 0..63
    const int j  = wkid & 15;          // supertile 0..15 (128 q rows each)

    const int q0 = j * 128 + wave * 16 + lm;
    const int q1 = q0 + 64;

    const unsigned short* Qh = Q + (size_t)bh * SEQ * HD;
    const unsigned short* Kh = K + (size_t)bh * SEQ * HD;
    const unsigned short* Vh = V + (size_t)bh * HD * SEQ;  // [d][s]

    short8 bq0[2], bq1[2];
#pragma unroll
    for (int c = 0; c < 2; c++) {
        bq0[c] = *(const short8*)(Qh + (size_t)q0 * HD + c * 32 + lq * 8);
        bq1[c] = *(const short8*)(Qh + (size_t)q1 * HD + c * 32 + lq * 8);
    }

    floatx4 acc0[4] = {}, acc1[4] = {};
    float l0 = 0.f, l1 = 0.f;
    const float kA = 0.04508422002778011f;  // log2(e)/32

    const int lrow = lane >> 3, lg = lane & 7;

    for (int kt = 15; kt >= j; kt--) {
        __syncthreads();
        // K tile: 128 keys x 64 d
#pragma unroll
        for (int i = 0; i < 4; i++) {
            int rows8 = wave * 32 + i * 8;
            gll16(Kh + (size_t)(kt * 128 + rows8 + lrow) * HD + (lg ^ lrow) * 8,
                  Ks + rows8 * 64);
        }
        // V^T tile: 64 d x 128 keys
#pragma unroll
        for (int i = 0; i < 4; i++) {
            int rows4 = wave * 16 + i * 4;
            int row = rows4 + (lane >> 4);
            int g = (lane & 15) ^ (row & 15);
            gll16(Vh + (size_t)row * SEQ + kt * 128 + g * 8, Vs + rows4 * 128);
        }
        __syncthreads();

        PROCESS_Q2(q0, q1, bq0, bq1, acc0, acc1, l0, l1, (kt == j), kt);
    }

    const int b = bh >> 4, h = bh & 15;
    WRITE_O(q0, acc0, l0);
    WRITE_O(q1, acc1, l1);
}

// ---------------------------------------------------------------------------
// Row 2047 is fully masked -> uniform softmax over ALL keys -> mean of V.
// ---------------------------------------------------------------------------
__global__ __launch_bounds__(256, 2)
void row2047_kernel(const unsigned short* __restrict__ V,
                    unsigned short* __restrict__ O)
{
    __shared__ float red[256];
    const int bh = blockIdx.x;
    const int b = bh >> 4, h = bh & 15;
    const int t = threadIdx.x;
    const int d = t & 63, seg = t >> 6;
    const __fp16* Vh = (const __fp16*)V + (size_t)bh * HD * SEQ + (size_t)d * SEQ + seg * 512;
    float s = 0.f;
    for (int i = 0; i < 512; i += 8) {
        h8_t v = *(const h8_t*)(Vh + i);
#pragma unroll
        for (int j = 0; j < 8; j++) s += (float)v[j];
    }
    red[t] = s;
    __syncthreads();
    if (seg == 0) {
        float tot = red[d] + red[64 + d] + red[128 + d] + red[192 + d];
        O[(size_t)(b * SEQ + 2047) * D_MODEL + h * HD + d] = f2bf(tot * (1.f / 2048.f));
    }
}

// ======================= fallback (ws < 72 MiB) kernels =====================
__global__ __launch_bounds__(256, 2)
void gemm_qkv_kernel(const float* __restrict__ A,
                     const float* __restrict__ W0,
                     const float* __restrict__ W1,
                     const float* __restrict__ W2,
                     unsigned short* __restrict__ O0,
                     unsigned short* __restrict__ O1,
                     unsigned short* __restrict__ O2)
{
    const int K = 1024;
    const float* W;
    unsigned short* Out;
    if (blockIdx.z == 0)      { W = W0; Out = O0; }
    else if (blockIdx.z == 1) { W = W1; Out = O1; }
    else                      { W = W2; Out = O2; }

    __shared__ __align__(16) unsigned short As[128 * 64];
    __shared__ __align__(16) unsigned short Bs[128 * 64];

    const int t = threadIdx.x;
    const int wave = t >> 6, lane = t & 63;
    const int lm = lane & 15, lq = lane >> 4;
    const int wrow = (wave >> 1) * 64, wcol = (wave & 1) * 64;
    const int m0 = blockIdx.x * 128, n0 = blockIdx.y * 128;

    floatx4 acc[4][4] = {};

    for (int k0 = 0; k0 < K; k0 += 64) {
        __syncthreads();
#pragma unroll
        for (int rr = 0; rr < 4; rr++) {
            int p = rr * 256 + t;
            int row = p >> 3, g = p & 7;
            const float* pa = A + (size_t)(m0 + row) * K + k0 + g * 8;
            const float* pw = W + (size_t)(n0 + row) * K + k0 + g * 8;
            floatx4 a0 = *(const floatx4*)pa, a1 = *(const floatx4*)(pa + 4);
            floatx4 w0 = *(const floatx4*)pw, w1 = *(const floatx4*)(pw + 4);
            short8 va, vb;
#pragma unroll
            for (int d = 0; d < 4; d++) {
                va[d]     = (short)f2bf(a0[d]);
                va[4 + d] = (short)f2bf(a1[d]);
                vb[d]     = (short)f2bf(w0[d]);
                vb[4 + d] = (short)f2bf(w1[d]);
            }
            int dst = row * 8 + (g ^ (row & 7));
            *(short8*)(As + dst * 8) = va;
            *(short8*)(Bs + dst * 8) = vb;
        }
        __syncthreads();

        short8 af[4][2], bf[4][2];
#pragma unroll
        for (int i = 0; i < 4; i++)
#pragma unroll
            for (int c = 0; c < 2; c++) {
                int ra = wrow + i * 16 + lm;
                int rb = wcol + i * 16 + lm;
                int g = c * 4 + lq;
                af[i][c] = *(const short8*)(As + (ra * 8 + (g ^ (ra & 7))) * 8);
                bf[i][c] = *(const short8*)(Bs + (rb * 8 + (g ^ (rb & 7))) * 8);
            }
#pragma unroll
        for (int i = 0; i < 4; i++)
#pragma unroll
            for (int j = 0; j < 4; j++)
#pragma unroll
                for (int c = 0; c < 2; c++)
                    acc[i][j] = __builtin_amdgcn_mfma_f32_16x16x32_bf16(
                        af[i][c], bf[j][c], acc[i][j], 0, 0, 0);
    }

    const int zi = blockIdx.z;
#pragma unroll
    for (int i = 0; i < 4; i++)
#pragma unroll
        for (int j = 0; j < 4; j++)
#pragma unroll
            for (int r = 0; r < 4; r++) {
                int gm = m0 + wrow + i * 16 + lq * 4 + r;
                int gn = n0 + wcol + j * 16 + lm;
                int b = gm >> 11, s = gm & 2047;
                int h = gn >> 6, d = gn & 63;
                if (zi == 2) {
                    Out[((size_t)(b * NH + h) * HD + d) * SEQ + s] = f2h(acc[i][j][r]);
                } else {
                    Out[((size_t)(b * NH + h) * SEQ + s) * HD + d] = f2bf(acc[i][j][r]);
                }
            }
}

__global__ __launch_bounds__(256, 2)
void gemm_out_kernel(const unsigned short* __restrict__ Abf,
                     const float* __restrict__ W,
                     float* __restrict__ Out)
{
    const int K = 1024;
    __shared__ __align__(16) unsigned short As[128 * 64];
    __shared__ __align__(16) unsigned short Bs[128 * 64];

    const int t = threadIdx.x;
    const int wave = t >> 6, lane = t & 63;
    const int lm = lane & 15, lq = lane >> 4;
    const int wrow = (wave >> 1) * 64, wcol = (wave & 1) * 64;
    const int m0 = blockIdx.x * 128, n0 = blockIdx.y * 128;

    floatx4 acc[4][4] = {};

    for (int k0 = 0; k0 < K; k0 += 64) {
        __syncthreads();
#pragma unroll
        for (int rr = 0; rr < 4; rr++) {
            int p = rr * 256 + t;
            int row = p >> 3, g = p & 7;
            short8 va = *(const short8*)(Abf + (size_t)(m0 + row) * K + k0 + g * 8);
            const float* pw = W + (size_t)(n0 + row) * K + k0 + g * 8;
            floatx4 w0 = *(const floatx4*)pw, w1 = *(const floatx4*)(pw + 4);
            short8 vb;
#pragma unroll
            for (int d = 0; d < 4; d++) {
                vb[d]     = (short)f2bf(w0[d]);
                vb[4 + d] = (short)f2bf(w1[d]);
            }
            int dst = row * 8 + (g ^ (row & 7));
            *(short8*)(As + dst * 8) = va;
            *(short8*)(Bs + dst * 8) = vb;
        }
        __syncthreads();

        short8 af[4][2], bf[4][2];
#pragma unroll
        for (int i = 0; i < 4; i++)
#pragma unroll
            for (int c = 0; c < 2; c++) {
                int ra = wrow + i * 16 + lm;
                int rb = wcol + i * 16 + lm;
                int g = c * 4 + lq;
                af[i][c] = *(const short8*)(As + (ra * 8 + (g ^ (ra & 7))) * 8);
                bf[i][c] = *(const short8*)(Bs + (rb * 8 + (g ^ (rb & 7))) * 8);
            }
#pragma unroll
        for (int i = 0; i < 4; i++)
#pragma unroll
            for (int j = 0; j < 4; j++)
#pragma unroll
                for (int c = 0; c < 2; c++)
                    acc[i][j] = __builtin_amdgcn_mfma_f32_16x16x32_bf16(
                        af[i][c], bf[j][c], acc[i][j], 0, 0, 0);
    }

#pragma unroll
    for (int i = 0; i < 4; i++)
#pragma unroll
        for (int j = 0; j < 4; j++)
#pragma unroll
            for (int r = 0; r < 4; r++) {
                int gm = m0 + wrow + i * 16 + lq * 4 + r;
                int gn = n0 + wcol + j * 16 + lm;
                Out[(size_t)gm * D_MODEL + gn] = acc[i][j][r];
            }
}

extern "C" void kernel_launch(void* const* d_in, const int* in_sizes, int n_in,
                              void* d_out, int out_size, void* d_ws, size_t ws_size,
                              hipStream_t stream) {
    const float* x  = (const float*)d_in[0];
    const float* wq = (const float*)d_in[1];
    const float* wk = (const float*)d_in[2];
    const float* wv = (const float*)d_in[3];
    const float* wo = (const float*)d_in[4];

    unsigned short* ws = (unsigned short*)d_ws;
    const bool fast = ws_size >= (size_t)36 * 1024 * 1024 * 2;  // 72 MiB

    if (fast) {
        unsigned short* xbf  = ws;                     // 8M elems; reused as Ob
        unsigned short* wqkv = ws + (size_t)ELEMS;     // 3M
        unsigned short* wobf = ws + (size_t)ELEMS + 3 * WELEMS;  // 1M
        unsigned short* Qb   = ws + (size_t)ELEMS + 4 * WELEMS;  // 8M
        unsigned short* Kb   = Qb + ELEMS;
        unsigned short* Vb   = Kb + ELEMS;
        unsigned short* Ob   = xbf;                    // x_bf dead after QKV GEMM

        cvt_kernel<<<6144, 256, 0, stream>>>(x, wq, wk, wv, wo, xbf, wqkv, wobf);
        gemm_qkv3_kernel<<<dim3(64, 24), 256, 0, stream>>>(xbf, wqkv, Qb, Kb, Vb);
        attn8_kernel<<<1024, 256, 0, stream>>>(Qb, Kb, Vb, Ob);
        row2047_kernel<<<BATCH * NH, 256, 0, stream>>>(Vb, Ob);
        gemm_out3_kernel<<<dim3(64, 8), 256, 0, stream>>>(Ob, wobf, (float*)d_out);
    } else {
        unsigned short* Qb = ws;
        unsigned short* Kb = Qb + ELEMS;
        unsigned short* Vb = Kb + ELEMS;
        unsigned short* Ob = Vb + ELEMS;

        gemm_qkv_kernel<<<dim3(64, 8, 3), 256, 0, stream>>>(x, wq, wk, wv, Qb, Kb, Vb);
        attn8_kernel<<<1024, 256, 0, stream>>>(Qb, Kb, Vb, Ob);
        row2047_kernel<<<BATCH * NH, 256, 0, stream>>>(Vb, Ob);
        gemm_out_kernel<<<dim3(64, 8), 256, 0, stream>>>(Ob, wo, (float*)d_out);
    }
}